// Round 9
// baseline (104.964 us; speedup 1.0000x reference)
//
#include <hip/hip_runtime.h>
#include <hip/hip_bf16.h>
#include <math.h>

// Shapes
#define QL 32768
#define DD 1024
#define NTOK 64

using short8   = __attribute__((ext_vector_type(8))) short;
using f32x4    = __attribute__((ext_vector_type(4))) float;
using float4v  = __attribute__((ext_vector_type(4))) float;
using ushort4v = __attribute__((ext_vector_type(4))) unsigned short;
using ushort8v = __attribute__((ext_vector_type(8))) unsigned short;

// RNE f32->bf16 via bit trick (exact RNE)
__device__ __forceinline__ unsigned short f2bf(float f) {
    unsigned int u = __float_as_uint(f);
    unsigned int r = (u + 0x7FFFu + ((u >> 16) & 1u)) >> 16;
    return (unsigned short)r;
}

// async global->LDS, 16B per lane; dest = wave-uniform base + lane*16
__device__ __forceinline__ void gload_lds16(const void* g, void* l) {
    __builtin_amdgcn_global_load_lds(
        (const __attribute__((address_space(1))) void*)g,
        (__attribute__((address_space(3))) void*)l,
        16, 0, 0);
}

// ---------------------------------------------------------------------------
// Prologue 1: transpose-convert Wq -> WqT bf16, Pv -> PvT bf16.
// ---------------------------------------------------------------------------
__global__ __launch_bounds__(256) void prep_transpose_kernel(
        const float* __restrict__ Wq, const float* __restrict__ Pv,
        unsigned short* __restrict__ WqT, unsigned short* __restrict__ PvT) {
    __shared__ float tile[64][65];
    int b = blockIdx.x;
    const float* src; unsigned short* dst; int R, C, r0, c0;
    if (b < 256) { src = Wq; dst = WqT; R = 1024; C = 1024;
                   r0 = (b >> 4) << 6; c0 = (b & 15) << 6; }
    else         { b -= 256; src = Pv; dst = PvT; R = 64; C = 1024;
                   r0 = 0; c0 = b << 6; }
    const int tid = threadIdx.x;
#pragma unroll
    for (int i = 0; i < 16; ++i) {
        const int lin = tid + 256 * i;
        const int row = lin >> 6, col = lin & 63;
        if (r0 + row < R)
            tile[row][col] = src[(size_t)(r0 + row) * C + c0 + col];
    }
    __syncthreads();
#pragma unroll
    for (int i = 0; i < 16; ++i) {
        const int lin = tid + 256 * i;
        const int row = lin >> 6, col = lin & 63;
        if (r0 + col < R)
            dst[(size_t)(c0 + row) * R + r0 + col] = f2bf(tile[col][row]);
    }
}

// ---------------------------------------------------------------------------
// Prologue 2: Kp = Pk @ Wq via bf16 MFMA (B from WqT). grid 16 x 256.
// ---------------------------------------------------------------------------
__global__ __launch_bounds__(256) void kp_mfma_kernel(
        const float* __restrict__ Pk, const unsigned short* __restrict__ WqT,
        unsigned short* __restrict__ Kp) {
    const int tid = threadIdx.x;
    const int w   = tid >> 6;
    const int l   = tid & 63;
    const int lhi = l >> 4;
    const int llo = l & 15;
    const int N0  = blockIdx.x * 64;

    f32x4 acc[4];
#pragma unroll
    for (int ct = 0; ct < 4; ++ct) acc[ct] = (f32x4){0.f, 0.f, 0.f, 0.f};

    for (int kb = 0; kb < 32; ++kb) {
        const int k0 = kb * 32 + lhi * 8;
        float4v p0 = *(const float4v*)(Pk + (size_t)(w * 16 + llo) * DD + k0);
        float4v p1 = *(const float4v*)(Pk + (size_t)(w * 16 + llo) * DD + k0 + 4);
        short8 a;
        a[0] = (short)f2bf(p0.x); a[1] = (short)f2bf(p0.y);
        a[2] = (short)f2bf(p0.z); a[3] = (short)f2bf(p0.w);
        a[4] = (short)f2bf(p1.x); a[5] = (short)f2bf(p1.y);
        a[6] = (short)f2bf(p1.z); a[7] = (short)f2bf(p1.w);
#pragma unroll
        for (int ct = 0; ct < 4; ++ct) {
            short8 b = *(const short8*)(WqT + (size_t)(N0 + ct * 16 + llo) * DD + k0);
            acc[ct] = __builtin_amdgcn_mfma_f32_16x16x32_bf16(a, b, acc[ct], 0, 0, 0);
        }
    }
#pragma unroll
    for (int ct = 0; ct < 4; ++ct) {
#pragma unroll
        for (int j = 0; j < 4; ++j) {
            const int t = w * 16 + lhi * 4 + j;
            const int d = N0 + ct * 16 + llo;
            Kp[(size_t)t * DD + d] = f2bf(acc[ct][j]);
        }
    }
}

// ---------------------------------------------------------------------------
// GEMM1: s' = gelu(l2norm_scale(x @ Kp^T)) -> sp bf16 [32768][64].
// grid 1024 x 256 (4 waves). Block = 32 q-rows. 16 K-steps of 64.
// 3-deep LDS circular buffer (48 KB -> 3 blocks/CU), global_load_lds staging
// of A (x fp32, 8 KB/step) and B (Kp bf16, 8 KB/step). Counted
// s_waitcnt vmcnt(4) + raw s_barrier per step (T3/T4); 2-step lookahead.
// Swizzle rule #21: linear LDS dest, inverse-swizzled global src, swizzled read.
// Epilogue: cross-wave reduce in LDS alias -> row l2-norm*8 -> exact GELU
// -> coalesced short8 stores to sp.
// ---------------------------------------------------------------------------
__global__ __launch_bounds__(256) void gemm1_kernel(
        const float* __restrict__ x, const unsigned short* __restrict__ Kp,
        unsigned short* __restrict__ sp) {
    __shared__ __align__(16) unsigned char smem[49152];

    const int tid = threadIdx.x;
    const int w   = tid >> 6;
    const int l   = tid & 63;
    const int lhi = l >> 4;    // 0..3
    const int llo = l & 15;    // 0..15
    const int R0  = blockIdx.x * 32;
    const char* xb  = (const char*)x;
    const char* kpb = (const char*)Kp;

    f32x4 acc[2];
    acc[0] = (f32x4){0.f, 0.f, 0.f, 0.f};
    acc[1] = (f32x4){0.f, 0.f, 0.f, 0.f};

#define BUFA(b) (smem + (b) * 8192)
#define BUFB(b) (smem + 24576 + (b) * 8192)

    // stage K-step t into circular buffer t%3: per wave 2 A-instrs + 2 B-instrs.
    // A tile [32 rows][64 k f32]: instr i rows i*4..+4; lane: row = i*4+(l>>4),
    //   chunk16 = l&15, src chunk pre-XOR'ed ((row&7)<<1)  (32B-granule XOR).
    // B tile [64 t][64 k bf16]: instr i rows i*8..+8; lane: row = i*8+(l>>3),
    //   chunk16 = l&7, src chunk pre-XOR'ed (row&7).
#define STAGE(t)                                                                \
    {                                                                           \
        const int bf_ = (t) % 3;                                                \
        _Pragma("unroll")                                                       \
        for (int j = 0; j < 2; ++j) {                                           \
            const int i  = w * 2 + j;                                           \
            const int ar = i * 4 + (l >> 4);                                    \
            const int ac = (l & 15) ^ ((ar & 7) << 1);                          \
            gload_lds16(xb + (size_t)(R0 + ar) * 4096 + (t) * 256 + ac * 16,    \
                        (void*)(BUFA(bf_) + i * 1024));                         \
            const int br = i * 8 + (l >> 3);                                    \
            const int bc = (l & 7) ^ (br & 7);                                  \
            gload_lds16(kpb + (size_t)br * 2048 + (t) * 128 + bc * 16,          \
                        (void*)(BUFB(bf_) + i * 1024));                         \
        }                                                                       \
    }

    // compute K-step t: wave w owns tokens w*16..w*16+16; 2 row-frags x 2 k-subs.
#define COMPUTE(t)                                                              \
    {                                                                           \
        const int bf_ = (t) % 3;                                                \
        _Pragma("unroll")                                                       \
        for (int ks = 0; ks < 2; ++ks) {                                        \
            const int brow = w * 16 + llo;                                      \
            const short8 b = *(const short8*)(BUFB(bf_) + brow * 128 +          \
                                  (((ks * 4 + lhi) ^ (brow & 7)) << 4));        \
            _Pragma("unroll")                                                   \
            for (int rf = 0; rf < 2; ++rf) {                                    \
                const int arow  = rf * 16 + llo;                                \
                const int abyte = arow * 256 +                                  \
                                  (((ks * 4 + lhi) ^ (arow & 7)) << 5);         \
                const float4v f0 = *(const float4v*)(BUFA(bf_) + abyte);        \
                const float4v f1 = *(const float4v*)(BUFA(bf_) + abyte + 16);   \
                short8 a;                                                       \
                ((__hip_bfloat162*)&a)[0] = __float22bfloat162_rn(float2{f0.x, f0.y}); \
                ((__hip_bfloat162*)&a)[1] = __float22bfloat162_rn(float2{f0.z, f0.w}); \
                ((__hip_bfloat162*)&a)[2] = __float22bfloat162_rn(float2{f1.x, f1.y}); \
                ((__hip_bfloat162*)&a)[3] = __float22bfloat162_rn(float2{f1.z, f1.w}); \
                acc[rf] = __builtin_amdgcn_mfma_f32_16x16x32_bf16(a, b, acc[rf], 0, 0, 0); \
            }                                                                   \
        }                                                                       \
    }

    // ---- prologue stages 2 steps; loop keeps 2 steps in flight ----
    STAGE(0); STAGE(1);
#pragma unroll
    for (int t = 0; t < 16; ++t) {
        if (t < 15) { asm volatile("s_waitcnt vmcnt(4)" ::: "memory"); }
        else        { asm volatile("s_waitcnt vmcnt(0)" ::: "memory"); }
        __builtin_amdgcn_s_barrier();
        __builtin_amdgcn_sched_barrier(0);
        if (t < 14) { STAGE(t + 2); }   // overwrites buf (t-1)%3: safe after barrier
        COMPUTE(t);
    }
#undef STAGE
#undef COMPUTE

    __syncthreads();   // all LDS reads of step 15 done before aliasing

    // ---- cross-wave partials -> LDS alias, row l2-norm*8 + GELU -> sp ----
    float (*sSf)[68] = (float (*)[68])(void*)smem;         // [32][68] f32, 8.7 KB
#pragma unroll
    for (int rf = 0; rf < 2; ++rf)
#pragma unroll
        for (int j = 0; j < 4; ++j)
            sSf[rf * 16 + lhi * 4 + j][w * 16 + llo] = acc[rf][j];
    __syncthreads();

    {
        const int r = tid >> 3;           // 0..31 q-row
        const int g = tid & 7;            // token group of 8
        const f32x4 v0 = *(const f32x4*)&sSf[r][g * 8];
        const f32x4 v1 = *(const f32x4*)&sSf[r][g * 8 + 4];
        float ssq = v0.x * v0.x + v0.y * v0.y + v0.z * v0.z + v0.w * v0.w
                  + v1.x * v1.x + v1.y * v1.y + v1.z * v1.z + v1.w * v1.w;
        ssq += __shfl_xor(ssq, 1);
        ssq += __shfl_xor(ssq, 2);
        ssq += __shfl_xor(ssq, 4);
        const float scale = 8.0f / sqrtf(ssq);
        short8 gq;
#pragma unroll
        for (int k = 0; k < 4; ++k) {
            const float a0 = v0[k] * scale;
            const float a1 = v1[k] * scale;
            gq[k]     = (short)f2bf(0.5f * a0 * (1.0f + erff(a0 * 0.70710678118654752f)));
            gq[4 + k] = (short)f2bf(0.5f * a1 * (1.0f + erff(a1 * 0.70710678118654752f)));
        }
        *(short8*)(sp + (size_t)(R0 + r) * 64 + g * 8) = gq;   // 16 B/lane coalesced
    }
#undef BUFA
#undef BUFB
}

// ---------------------------------------------------------------------------
// GEMM2: y[32768][1024] = s'(bf16) @ Pv, swapped MFMA (D[m=d][n=q]),
// float4 stores. grid 2048 x 256 (4 waves); block = 16 q-rows; wave = 256 d-cols.
// Pure write-stream kernel: s' + PvT are L2-resident; only stores hit HBM.
// ---------------------------------------------------------------------------
__global__ __launch_bounds__(256, 4) void gemm2_kernel(
        const unsigned short* __restrict__ sp, const unsigned short* __restrict__ PvT,
        float* __restrict__ out) {
    __shared__ __align__(16) unsigned char sS[16 * 128];  // s' [16][64] bf16 swizzled

    const int tid = threadIdx.x;
    const int w   = tid >> 6;
    const int l   = tid & 63;
    const int lhi = l >> 4;
    const int llo = l & 15;
    const int R0  = blockIdx.x * 16;

    // stage s' tile (2KB) coalesced, swizzled
    if (tid < 128) {
        const int o = tid * 16;             // flat byte in [16][128]
        const int q = o >> 7;
        ushort8v v = *(const ushort8v*)(sp + (size_t)R0 * 64 + tid * 8);
        *(ushort8v*)(sS + (o ^ ((q & 7) << 4))) = v;
    }
    __syncthreads();

    short8 sb0 = *(const short8*)(sS + ((llo * 128 + lhi * 16)      ^ ((llo & 7) << 4)));
    short8 sb1 = *(const short8*)(sS + ((llo * 128 + 64 + lhi * 16) ^ ((llo & 7) << 4)));

    const int N0w = w * 256;
    float* orow = out + (size_t)(R0 + llo) * DD + N0w + lhi * 4;
#pragma unroll 4
    for (int dt = 0; dt < 16; ++dt) {
        const unsigned short* ap = PvT + (size_t)(N0w + dt * 16 + llo) * 64 + lhi * 8;
        short8 pa0 = *(const short8*)ap;
        short8 pa1 = *(const short8*)(ap + 32);
        f32x4 acc2 = (f32x4){0.f, 0.f, 0.f, 0.f};
        acc2 = __builtin_amdgcn_mfma_f32_16x16x32_bf16(pa0, sb0, acc2, 0, 0, 0);
        acc2 = __builtin_amdgcn_mfma_f32_16x16x32_bf16(pa1, sb1, acc2, 0, 0, 0);
        *(float4v*)(orow + dt * 16) = acc2;
    }
}

// ---------------------------------------------------------------------------
extern "C" void kernel_launch(void* const* d_in, const int* in_sizes, int n_in,
                              void* d_out, int out_size, void* d_ws, size_t ws_size,
                              hipStream_t stream) {
    (void)in_sizes; (void)n_in; (void)out_size; (void)ws_size;
    const float* x  = (const float*)d_in[0];
    const float* Wq = (const float*)d_in[1];
    const float* Pk = (const float*)d_in[2];
    const float* Pv = (const float*)d_in[3];
    float* out = (float*)d_out;

    // ws layout (6.25 MB total):
    //   WqT bf16 [1024][1024] @ 0            (2 MB)
    //   Kp  bf16 [64][1024]   @ 2 MB         (128 KB)
    //   PvT bf16 [1024][64]   @ 2 MB + 128K  (128 KB)
    //   s'  bf16 [32768][64]  @ 2.25 MB      (4 MB)
    unsigned short* WqT = (unsigned short*)d_ws;
    unsigned short* Kp  = (unsigned short*)((char*)d_ws + 2097152);
    unsigned short* PvT = (unsigned short*)((char*)d_ws + 2097152 + 131072);
    unsigned short* sp  = (unsigned short*)((char*)d_ws + 2097152 + 262144);

    prep_transpose_kernel<<<272, 256, 0, stream>>>(Wq, Pv, WqT, PvT);
    kp_mfma_kernel<<<16, 256, 0, stream>>>(Pk, WqT, Kp);
    gemm1_kernel<<<1024, 256, 0, stream>>>(x, Kp, sp);
    gemm2_kernel<<<2048, 256, 0, stream>>>(sp, PvT, out);
}

// Round 10
// 80.811 us; speedup vs baseline: 1.2989x; 1.2989x over previous
//
#include <hip/hip_runtime.h>
#include <hip/hip_bf16.h>
#include <math.h>

// Shapes
#define QL 32768
#define DD 1024
#define NTOK 64

using short8   = __attribute__((ext_vector_type(8))) short;
using f32x4    = __attribute__((ext_vector_type(4))) float;
using float4v  = __attribute__((ext_vector_type(4))) float;
using ushort4v = __attribute__((ext_vector_type(4))) unsigned short;
using ushort8v = __attribute__((ext_vector_type(8))) unsigned short;

// RNE f32->bf16 via bit trick (exact RNE)
__device__ __forceinline__ unsigned short f2bf(float f) {
    unsigned int u = __float_as_uint(f);
    unsigned int r = (u + 0x7FFFu + ((u >> 16) & 1u)) >> 16;
    return (unsigned short)r;
}

// async global->LDS, 16B per lane; dest = wave-uniform base + lane*16
__device__ __forceinline__ void gload_lds16(const void* g, void* l) {
    __builtin_amdgcn_global_load_lds(
        (const __attribute__((address_space(1))) void*)g,
        (__attribute__((address_space(3))) void*)l,
        16, 0, 0);
}

// ---------------------------------------------------------------------------
// Prologue 1: transpose-convert Wq -> WqT bf16, Pv -> PvT bf16.
// ---------------------------------------------------------------------------
__global__ __launch_bounds__(256) void prep_transpose_kernel(
        const float* __restrict__ Wq, const float* __restrict__ Pv,
        unsigned short* __restrict__ WqT, unsigned short* __restrict__ PvT) {
    __shared__ float tile[64][65];
    int b = blockIdx.x;
    const float* src; unsigned short* dst; int R, C, r0, c0;
    if (b < 256) { src = Wq; dst = WqT; R = 1024; C = 1024;
                   r0 = (b >> 4) << 6; c0 = (b & 15) << 6; }
    else         { b -= 256; src = Pv; dst = PvT; R = 64; C = 1024;
                   r0 = 0; c0 = b << 6; }
    const int tid = threadIdx.x;
#pragma unroll
    for (int i = 0; i < 16; ++i) {
        const int lin = tid + 256 * i;
        const int row = lin >> 6, col = lin & 63;
        if (r0 + row < R)
            tile[row][col] = src[(size_t)(r0 + row) * C + c0 + col];
    }
    __syncthreads();
#pragma unroll
    for (int i = 0; i < 16; ++i) {
        const int lin = tid + 256 * i;
        const int row = lin >> 6, col = lin & 63;
        if (r0 + col < R)
            dst[(size_t)(c0 + row) * R + r0 + col] = f2bf(tile[col][row]);
    }
}

// ---------------------------------------------------------------------------
// Prologue 2: Kp = Pk @ Wq via bf16 MFMA (B from WqT). grid 16 x 256.
// ---------------------------------------------------------------------------
__global__ __launch_bounds__(256) void kp_mfma_kernel(
        const float* __restrict__ Pk, const unsigned short* __restrict__ WqT,
        unsigned short* __restrict__ Kp) {
    const int tid = threadIdx.x;
    const int w   = tid >> 6;
    const int l   = tid & 63;
    const int lhi = l >> 4;
    const int llo = l & 15;
    const int N0  = blockIdx.x * 64;

    f32x4 acc[4];
#pragma unroll
    for (int ct = 0; ct < 4; ++ct) acc[ct] = (f32x4){0.f, 0.f, 0.f, 0.f};

    for (int kb = 0; kb < 32; ++kb) {
        const int k0 = kb * 32 + lhi * 8;
        float4v p0 = *(const float4v*)(Pk + (size_t)(w * 16 + llo) * DD + k0);
        float4v p1 = *(const float4v*)(Pk + (size_t)(w * 16 + llo) * DD + k0 + 4);
        short8 a;
        a[0] = (short)f2bf(p0.x); a[1] = (short)f2bf(p0.y);
        a[2] = (short)f2bf(p0.z); a[3] = (short)f2bf(p0.w);
        a[4] = (short)f2bf(p1.x); a[5] = (short)f2bf(p1.y);
        a[6] = (short)f2bf(p1.z); a[7] = (short)f2bf(p1.w);
#pragma unroll
        for (int ct = 0; ct < 4; ++ct) {
            short8 b = *(const short8*)(WqT + (size_t)(N0 + ct * 16 + llo) * DD + k0);
            acc[ct] = __builtin_amdgcn_mfma_f32_16x16x32_bf16(a, b, acc[ct], 0, 0, 0);
        }
    }
#pragma unroll
    for (int ct = 0; ct < 4; ++ct) {
#pragma unroll
        for (int j = 0; j < 4; ++j) {
            const int t = w * 16 + lhi * 4 + j;
            const int d = N0 + ct * 16 + llo;
            Kp[(size_t)t * DD + d] = f2bf(acc[ct][j]);
        }
    }
}

// ---------------------------------------------------------------------------
// Fused main kernel: s = x @ Kp^T -> row l2-norm*8 -> exact GELU -> y = s' @ Pv.
// grid 256 x 512 (8 waves), 128 q-rows/block (1 block/CU).
// Traffic per block: x 512 KB (once) + Kp 128 KB + PvT 128 KB + y 512 KB
//   -> chip total ~332 MB (vs 524 MB at 1024 blocks): BW-bound redesign.
// Phase A: 16 K-steps of 64. 3-deep circular LDS bufs, global_load_lds for
//   A (x fp32 [128][64], 32 KB/step) and B (Kp bf16 [64][64], 8 KB/step);
//   counted s_waitcnt vmcnt(5) (= ops/thread/step) + raw s_barrier per step.
//   Wave (wr,wt): rows wr*64..+64, tokens wt*16..+16. Swizzle rule #21.
// Phase B: partial s -> sSf[128][68] (alias dead A-bufs) -> 4-lane shfl norm
//   -> exact GELU -> s' bf16 [128][64] swizzled (alias dead B-bufs).
// Phase C: y = s' @ Pv swapped MFMA (D[m=d][n=q]); s'-frags in 64 VGPR,
//   PvT frags from L2; float4 stores. Wave w owns d-cols w*128..+128.
// ---------------------------------------------------------------------------
__global__ __launch_bounds__(512) void pattn_kernel(
        const float* __restrict__ x, const unsigned short* __restrict__ Kp,
        const unsigned short* __restrict__ PvT, float* __restrict__ out) {
    __shared__ __align__(16) unsigned char smem[122880];   // 3*32K (A) + 3*8K (B)

    const int tid = threadIdx.x;
    const int w   = tid >> 6;     // 0..7
    const int l   = tid & 63;
    const int lhi = l >> 4;       // 0..3
    const int llo = l & 15;       // 0..15
    const int wr  = w >> 2;       // 0..1  row-half
    const int wt  = w & 3;        // 0..3  token-slice
    const int R0  = blockIdx.x * 128;
    const char* xb  = (const char*)x;
    const char* kpb = (const char*)Kp;

    f32x4 acc[4];
#pragma unroll
    for (int rf = 0; rf < 4; ++rf) acc[rf] = (f32x4){0.f, 0.f, 0.f, 0.f};

#define ABUF(t) (smem + ((t) % 3) * 32768)
#define BBUF(t) (smem + 98304 + ((t) % 3) * 8192)

    // stage K-step t: 4 A-gloads + 1 B-gload per thread (5 vm ops/step).
    // A [128 rows][16 chunks16]: LDS chunk c <- global chunk c ^ ((row&7)<<1).
    // B [64 rows][8 chunks16]:   LDS chunk c <- global chunk c ^ (row&7).
#define STAGE(t)                                                                \
    {                                                                           \
        unsigned char* abuf = ABUF(t);                                          \
        unsigned char* bbuf = BBUF(t);                                          \
        _Pragma("unroll")                                                       \
        for (int i = 0; i < 4; ++i) {                                           \
            const int row = i * 32 + w * 4 + (l >> 4);                          \
            const int csw = (l & 15) ^ ((row & 7) << 1);                        \
            gload_lds16(xb + (size_t)(R0 + row) * 4096 + (t) * 256 + csw * 16,  \
                        (void*)(abuf + (i * 32 + w * 4) * 256));                \
        }                                                                       \
        const int brow = w * 8 + (l >> 3);                                      \
        const int bcs  = (l & 7) ^ (brow & 7);                                  \
        gload_lds16(kpb + (size_t)brow * 2048 + (t) * 128 + bcs * 16,           \
                    (void*)(bbuf + (w * 8) * 128));                             \
    }

    // compute K-step t: wave (wr,wt): 2 k-subs x 4 row-frags = 8 MFMA.
#define COMPUTE(t)                                                              \
    {                                                                           \
        unsigned char* abuf = ABUF(t);                                          \
        unsigned char* bbuf = BBUF(t);                                          \
        _Pragma("unroll")                                                       \
        for (int ks = 0; ks < 2; ++ks) {                                        \
            const int btok = wt * 16 + llo;                                     \
            const short8 bfrg = *(const short8*)(bbuf + btok * 128 +            \
                                  (((ks * 4 + lhi) ^ (btok & 7)) << 4));        \
            _Pragma("unroll")                                                   \
            for (int rf = 0; rf < 4; ++rf) {                                    \
                const int arow  = wr * 64 + rf * 16 + llo;                      \
                const int abyte = arow * 256 +                                  \
                                  (((ks * 4 + lhi) ^ (arow & 7)) << 5);         \
                const float4v f0 = *(const float4v*)(abuf + abyte);             \
                const float4v f1 = *(const float4v*)(abuf + abyte + 16);        \
                short8 a;                                                       \
                ((__hip_bfloat162*)&a)[0] = __float22bfloat162_rn(float2{f0.x, f0.y}); \
                ((__hip_bfloat162*)&a)[1] = __float22bfloat162_rn(float2{f0.z, f0.w}); \
                ((__hip_bfloat162*)&a)[2] = __float22bfloat162_rn(float2{f1.x, f1.y}); \
                ((__hip_bfloat162*)&a)[3] = __float22bfloat162_rn(float2{f1.z, f1.w}); \
                acc[rf] = __builtin_amdgcn_mfma_f32_16x16x32_bf16(a, bfrg, acc[rf], 0, 0, 0); \
            }                                                                   \
        }                                                                       \
    }

    // ---- Phase A: depth-3 pipeline, 2-step lookahead, counted vmcnt ----
    STAGE(0); STAGE(1);
#pragma unroll
    for (int t = 0; t < 16; ++t) {
        if (t < 15) { asm volatile("s_waitcnt vmcnt(5)" ::: "memory"); }
        else        { asm volatile("s_waitcnt vmcnt(0)" ::: "memory"); }
        __builtin_amdgcn_s_barrier();
        __builtin_amdgcn_sched_barrier(0);
        if (t < 14) STAGE(t + 2);
        COMPUTE(t);
    }
#undef STAGE
#undef COMPUTE
#undef ABUF
#undef BBUF

    __syncthreads();   // pipeline fully retired -> LDS free for aliases

    // ---- Phase B: partials -> sSf, 4-lane norm, exact GELU -> s' LDS ----
    float (*sSf)[68] = (float (*)[68])(void*)smem;          // [128][68] f32, 34.8 KB
#pragma unroll
    for (int rf = 0; rf < 4; ++rf)
#pragma unroll
        for (int j = 0; j < 4; ++j)
            sSf[wr * 64 + rf * 16 + lhi * 4 + j][wt * 16 + llo] = acc[rf][j];
    __syncthreads();

    unsigned char* sP = smem + 98304;                       // s' [128][128B] swizzled, 16 KB
    {
        const int r  = tid >> 2;          // 0..127 q-row
        const int tq = tid & 3;           // 16-token slice
        const f32x4 v0 = *(const f32x4*)&sSf[r][tq * 16];
        const f32x4 v1 = *(const f32x4*)&sSf[r][tq * 16 + 4];
        const f32x4 v2 = *(const f32x4*)&sSf[r][tq * 16 + 8];
        const f32x4 v3 = *(const f32x4*)&sSf[r][tq * 16 + 12];
        float ssq = v0.x*v0.x + v0.y*v0.y + v0.z*v0.z + v0.w*v0.w
                  + v1.x*v1.x + v1.y*v1.y + v1.z*v1.z + v1.w*v1.w
                  + v2.x*v2.x + v2.y*v2.y + v2.z*v2.z + v2.w*v2.w
                  + v3.x*v3.x + v3.y*v3.y + v3.z*v3.z + v3.w*v3.w;
        ssq += __shfl_xor(ssq, 1);
        ssq += __shfl_xor(ssq, 2);
        const float scale = 8.0f / sqrtf(ssq);
        short8 g0, g1;
#pragma unroll
        for (int k = 0; k < 4; ++k) {
            const float a0 = v0[k] * scale, a1 = v1[k] * scale;
            const float a2 = v2[k] * scale, a3 = v3[k] * scale;
            g0[k]     = (short)f2bf(0.5f * a0 * (1.0f + erff(a0 * 0.70710678118654752f)));
            g0[4 + k] = (short)f2bf(0.5f * a1 * (1.0f + erff(a1 * 0.70710678118654752f)));
            g1[k]     = (short)f2bf(0.5f * a2 * (1.0f + erff(a2 * 0.70710678118654752f)));
            g1[4 + k] = (short)f2bf(0.5f * a3 * (1.0f + erff(a3 * 0.70710678118654752f)));
        }
        // store token-chunks 2tq, 2tq+1 with chunk XOR (r&7)
        *(short8*)(sP + r * 128 + (((2 * tq)     ^ (r & 7)) << 4)) = g0;
        *(short8*)(sP + r * 128 + (((2 * tq + 1) ^ (r & 7)) << 4)) = g1;
    }
    __syncthreads();

    // ---- Phase C: y = s' @ Pv (swapped: D[m=d][n=q]); float4 stores ----
    short8 sfr[8][2];
#pragma unroll
    for (int qb = 0; qb < 8; ++qb)
#pragma unroll
        for (int ks = 0; ks < 2; ++ks) {
            const int q = qb * 16 + llo;
            sfr[qb][ks] = *(const short8*)(sP + q * 128 +
                              (((ks * 4 + lhi) ^ (q & 7)) << 4));
        }

    const int d0 = w * 128;
#pragma unroll 2
    for (int dt = 0; dt < 8; ++dt) {
        const unsigned short* ap = PvT + (size_t)(d0 + dt * 16 + llo) * 64 + lhi * 8;
        const short8 pa0 = *(const short8*)ap;
        const short8 pa1 = *(const short8*)(ap + 32);
#pragma unroll
        for (int qb = 0; qb < 8; ++qb) {
            f32x4 c = (f32x4){0.f, 0.f, 0.f, 0.f};
            c = __builtin_amdgcn_mfma_f32_16x16x32_bf16(pa0, sfr[qb][0], c, 0, 0, 0);
            c = __builtin_amdgcn_mfma_f32_16x16x32_bf16(pa1, sfr[qb][1], c, 0, 0, 0);
            *(float4v*)(out + (size_t)(R0 + qb * 16 + llo) * DD + d0 + dt * 16 + lhi * 4) = c;
        }
    }
}

// ---------------------------------------------------------------------------
extern "C" void kernel_launch(void* const* d_in, const int* in_sizes, int n_in,
                              void* d_out, int out_size, void* d_ws, size_t ws_size,
                              hipStream_t stream) {
    (void)in_sizes; (void)n_in; (void)out_size; (void)ws_size;
    const float* x  = (const float*)d_in[0];
    const float* Wq = (const float*)d_in[1];
    const float* Pk = (const float*)d_in[2];
    const float* Pv = (const float*)d_in[3];
    float* out = (float*)d_out;

    // ws layout (2.25 MB total):
    //   WqT bf16 [1024][1024] @ 0            (2 MB)
    //   Kp  bf16 [64][1024]   @ 2 MB         (128 KB)
    //   PvT bf16 [1024][64]   @ 2 MB + 128K  (128 KB)
    unsigned short* WqT = (unsigned short*)d_ws;
    unsigned short* Kp  = (unsigned short*)((char*)d_ws + 2097152);
    unsigned short* PvT = (unsigned short*)((char*)d_ws + 2097152 + 131072);

    prep_transpose_kernel<<<272, 256, 0, stream>>>(Wq, Pv, WqT, PvT);
    kp_mfma_kernel<<<16, 256, 0, stream>>>(Pk, WqT, Kp);
    pattn_kernel<<<256, 512, 0, stream>>>(x, Kp, PvT, out);
}